// Round 2
// baseline (116.235 us; speedup 1.0000x reference)
//
#include <hip/hip_runtime.h>

// out0 = 0.5*(1 + cos(th)*cos(x0) - sin(th)*sin(x0)*sin(x1))
// out1 = 0.5*(1 + cos(x0)*cos(x1))
// Product-to-sum: with u = x0+x1, v = x0-x1:
//   s0*s1 = 0.5*(cos(v) - cos(u)),  c0*c1 = 0.5*(cos(u) + cos(v))
// -> 3 cos per batch element (6/thread) instead of 4 sincos pairs.
// Streaming kernel: 16 B in + 16 B out per thread, zero reuse ->
// non-temporal loads/stores (nt flag) to keep streams out of L2.
// NOTE: __builtin_nontemporal_* requires a NATIVE vector type, not
// HIP_vector_type<float,4> — hence the ext_vector_type alias.

typedef float v4f __attribute__((ext_vector_type(4)));

__global__ __launch_bounds__(256) void qc_kernel(
    const v4f* __restrict__ x4,
    const float* __restrict__ theta,
    v4f* __restrict__ out4,
    int n4)
{
    int i = blockIdx.x * blockDim.x + threadIdx.x;
    if (i >= n4) return;

    // theta is wave-uniform; broadcast load + 2 transcendentals
    float th = theta[0];
    float ct = __cosf(th);
    float st = __sinf(th);

    v4f v = __builtin_nontemporal_load(&x4[i]);  // (x0, x1, x0', x1')

    // element 0
    float c0 = __cosf(v.x);
    float cu = __cosf(v.x + v.y);   // cos(x0+x1)
    float cv = __cosf(v.x - v.y);   // cos(x0-x1)
    // element 1
    float c2 = __cosf(v.z);
    float cu2 = __cosf(v.z + v.w);
    float cv2 = __cosf(v.z - v.w);

    v4f o;
    o.x = 0.5f + 0.5f * ct * c0 - 0.25f * st * (cv - cu);
    o.y = 0.5f + 0.25f * (cu + cv);
    o.z = 0.5f + 0.5f * ct * c2 - 0.25f * st * (cv2 - cu2);
    o.w = 0.5f + 0.25f * (cu2 + cv2);

    __builtin_nontemporal_store(o, &out4[i]);
}

extern "C" void kernel_launch(void* const* d_in, const int* in_sizes, int n_in,
                              void* d_out, int out_size, void* d_ws, size_t ws_size,
                              hipStream_t stream) {
    const float* x     = (const float*)d_in[0];  // [B,2] flat
    const float* theta = (const float*)d_in[1];  // [1]
    float* out         = (float*)d_out;          // [B,2] flat

    int n  = in_sizes[0];      // total floats = 2*B (divisible by 4)
    int n4 = n / 4;

    const int block = 256;
    int grid = (n4 + block - 1) / block;

    qc_kernel<<<grid, block, 0, stream>>>(
        (const v4f*)x, theta, (v4f*)out, n4);
}

// Round 3
// 111.345 us; speedup vs baseline: 1.0439x; 1.0439x over previous
//
#include <hip/hip_runtime.h>

// out0 = 0.5*(1 + cos(th)*cos(x0) - sin(th)*sin(x0)*sin(x1))
// out1 = 0.5*(1 + cos(x0)*cos(x1))
// Product-to-sum: with u = x0+x1, v = x0-x1:
//   s0*s1 = 0.5*(cos(v) - cos(u)),  c0*c1 = 0.5*(cos(u) + cos(v))
// -> 3 cos per batch element (6/thread-pair) instead of 4 sincos pairs.
//
// R1 lesson: __builtin_nontemporal_* REGRESSED (110.6 -> 116.2 us) —
// nt bypasses L2/L3 allocation and the plain streaming-store path is
// faster on gfx950. Reverted to plain loads/stores.
//
// MLP: each thread processes TWO independent float4s (i and i+half,
// both coalesced streams) -> 2 outstanding dwordx4 loads per thread,
// half the blocks; cos-chain of pair A overlaps load latency of pair B.

__global__ __launch_bounds__(256) void qc_kernel(
    const float4* __restrict__ x4,
    const float* __restrict__ theta,
    float4* __restrict__ out4,
    int half, int n4)
{
    int i = blockIdx.x * blockDim.x + threadIdx.x;
    if (i >= half) return;

    // theta is wave-uniform; broadcast load + 2 transcendentals
    float th = theta[0];
    float ct = __cosf(th);
    float st = __sinf(th);

    int j = i + half;
    bool has_j = (j < n4);

    float4 a = x4[i];                      // (x0, x1, x0', x1')
    float4 b = has_j ? x4[j] : a;

    // pair A
    float c0  = __cosf(a.x);
    float cu0 = __cosf(a.x + a.y);
    float cv0 = __cosf(a.x - a.y);
    float c1  = __cosf(a.z);
    float cu1 = __cosf(a.z + a.w);
    float cv1 = __cosf(a.z - a.w);
    // pair B
    float c2  = __cosf(b.x);
    float cu2 = __cosf(b.x + b.y);
    float cv2 = __cosf(b.x - b.y);
    float c3  = __cosf(b.z);
    float cu3 = __cosf(b.z + b.w);
    float cv3 = __cosf(b.z - b.w);

    float4 oa, ob;
    oa.x = 0.5f + 0.5f * ct * c0 - 0.25f * st * (cv0 - cu0);
    oa.y = 0.5f + 0.25f * (cu0 + cv0);
    oa.z = 0.5f + 0.5f * ct * c1 - 0.25f * st * (cv1 - cu1);
    oa.w = 0.5f + 0.25f * (cu1 + cv1);

    ob.x = 0.5f + 0.5f * ct * c2 - 0.25f * st * (cv2 - cu2);
    ob.y = 0.5f + 0.25f * (cu2 + cv2);
    ob.z = 0.5f + 0.5f * ct * c3 - 0.25f * st * (cv3 - cu3);
    ob.w = 0.5f + 0.25f * (cu3 + cv3);

    out4[i] = oa;
    if (has_j) out4[j] = ob;
}

extern "C" void kernel_launch(void* const* d_in, const int* in_sizes, int n_in,
                              void* d_out, int out_size, void* d_ws, size_t ws_size,
                              hipStream_t stream) {
    const float* x     = (const float*)d_in[0];  // [B,2] flat
    const float* theta = (const float*)d_in[1];  // [1]
    float* out         = (float*)d_out;          // [B,2] flat

    int n    = in_sizes[0];     // total floats = 2*B (divisible by 4)
    int n4   = n / 4;
    int half = (n4 + 1) / 2;

    const int block = 256;
    int grid = (half + block - 1) / block;

    qc_kernel<<<grid, block, 0, stream>>>(
        (const float4*)x, theta, (float4*)out, half, n4);
}